// Round 8
// baseline (215.967 us; speedup 1.0000x reference)
//
#include <hip/hip_runtime.h>

#define DEV __device__ __forceinline__

typedef __attribute__((ext_vector_type(8))) short bf16x8;
typedef __attribute__((ext_vector_type(4))) float f32x4;

constexpr int Nn = 4096, Dd = 256, Kk = 128;
constexpr int RT = 64;       // rows per sub-tile
constexpr int TILES = 4;     // sub-tiles per block (256 rows)
constexpr int CHUNKS = 16;   // blocks per batch; grid = 32*16 = 512

DEV unsigned short f2bf(float f) {
  unsigned int u = __builtin_bit_cast(unsigned int, f);
  u += 0x7FFFu + ((u >> 16) & 1u);          // RNE; inputs are finite
  return (unsigned short)(u >> 16);
}
DEV float bf2f(unsigned short h) {
  unsigned int u = (unsigned int)h << 16;
  return __builtin_bit_cast(float, u);
}

// 128B LDS rows (64 bf16). XOR-swizzle bytes 4-6 by h(row)=(row&7)^(((row>>3)&3)<<1).
// Writes: per store instruction the 4 lane-groups hit disjoint bank quartets;
// reads (16 lanes, stride-128B rows): <=2-way. h is invariant under row+=32,
// so xT store addresses fold the per-ks step into a +4096B immediate.
DEV unsigned lds_addr(unsigned row, unsigned byteInRow) {
  unsigned h = (row & 7u) ^ (((row >> 3) & 3u) << 1);
  return row * 128u + (byteInRow ^ (h << 4));
}

__global__ void enc_prep(const float* __restrict__ cw, const float* __restrict__ sc,
                         unsigned short* __restrict__ cbf, float2* __restrict__ tab) {
  int k = blockIdx.x, l = threadIdx.x;          // 128 blocks x 64 threads
  float4 u = *(const float4*)(cw + k * Dd + l * 4);
  float s2 = u.x * u.x + u.y * u.y + u.z * u.z + u.w * u.w;
  #pragma unroll
  for (int o = 1; o < 64; o <<= 1) s2 += __shfl_xor(s2, o);
  unsigned short* dst = cbf + k * Dd + l * 4;
  dst[0] = f2bf(u.x); dst[1] = f2bf(u.y); dst[2] = f2bf(u.z); dst[3] = f2bf(u.w);
  if (l == 0) { float s = sc[k]; tab[k] = make_float2(s * s2, 2.0f * s); }
}

// PMODE: 0 = fp32 partials to Ep, 1 = bf16 partials to Ep, 2 = atomicAdd to out
template<int PMODE>
DEV void enc_impl(const float* __restrict__ x, const unsigned short* __restrict__ cbf,
                  const float2* __restrict__ tab, const float* __restrict__ cwf,
                  char* __restrict__ Ep, float* __restrict__ out) {
  // LDS: xT (256 x 64 bf16, swz) = 32KB ; W (128 x 64 bf16, swz) = 16KB ; misc 2KB
  // ~50KB total -> 2 blocks/CU at grid 512 -> 4 waves/SIMD (2x round-5 occupancy).
  __shared__ __align__(16) char smem[49152];
  __shared__ float WsumL[Kk];
  __shared__ float2 tabL[Kk];
  __shared__ float hs[2][RT];
  char* Wb = smem + 32768;

  const int tid = threadIdx.x;
  const int w  = tid >> 6;             // wave 0..7
  const int l  = tid & 63;
  const int g  = l >> 4;               // 16-lane group 0..3
  const int ln = l & 15;
  const int rgrp = w >> 1, h = w & 1;  // phase-1: row-group 0..3, cw-half 0..1
  const int wr = w >> 2, wc = w & 3;   // phase-2 wave grid 2x4 over E(128 x 256)
  const int b = blockIdx.x >> 4, chunk = blockIdx.x & 15;
  const int rowLoc = rgrp * 16 + ln;   // this lane's row within the 64-row sub-tile

  const float* xb = x + ((size_t)b * Nn + (size_t)chunk * (TILES * RT)) * Dd;

  if (tid < Kk) { WsumL[tid] = 0.0f; tabL[tid] = tab[tid]; }
  __syncthreads();

  f32x4 acc[4][4];
  const f32x4 zero4 = {0.f, 0.f, 0.f, 0.f};
  #pragma unroll
  for (int mi = 0; mi < 4; ++mi)
    #pragma unroll
    for (int ni = 0; ni < 4; ++ni) acc[mi][ni] = zero4;

  const unsigned colb = (unsigned)rowLoc * 2u;   // n-column (bytes) in xT/W rows
  unsigned a_st[8];
  #pragma unroll
  for (int i = 0; i < 8; ++i) a_st[i] = lds_addr((unsigned)(g * 8 + i), colb);

  for (int t = 0; t < TILES; ++t) {
    // -------- Phase 1: S^T = mfma(c_half, x); wave pair splits the 128 cw
    const float* xrow = xb + ((size_t)t * RT + rowLoc) * Dd;
    f32x4 s1[4];
    #pragma unroll
    for (int f = 0; f < 4; ++f) s1[f] = zero4;
    float x2p = 0.f;

    #pragma unroll
    for (int ks = 0; ks < 8; ++ks) {
      const int d0 = ks * 32 + g * 8;
      float4 u0 = *(const float4*)(xrow + d0);
      float4 u1 = *(const float4*)(xrow + d0 + 4);
      x2p += u0.x*u0.x + u0.y*u0.y + u0.z*u0.z + u0.w*u0.w
           + u1.x*u1.x + u1.y*u1.y + u1.z*u1.z + u1.w*u1.w;
      unsigned short q0 = f2bf(u0.x), q1 = f2bf(u0.y), q2 = f2bf(u0.z), q3 = f2bf(u0.w);
      unsigned short q4 = f2bf(u1.x), q5 = f2bf(u1.y), q6 = f2bf(u1.z), q7 = f2bf(u1.w);
      bf16x8 xv;
      xv[0] = (short)q0; xv[1] = (short)q1; xv[2] = (short)q2; xv[3] = (short)q3;
      xv[4] = (short)q4; xv[5] = (short)q5; xv[6] = (short)q6; xv[7] = (short)q7;
      if (h == 0) {   // pair-twin (h==1) shares these rows; one writer suffices
        *(unsigned short*)(smem + a_st[0] + ks * 4096) = q0;
        *(unsigned short*)(smem + a_st[1] + ks * 4096) = q1;
        *(unsigned short*)(smem + a_st[2] + ks * 4096) = q2;
        *(unsigned short*)(smem + a_st[3] + ks * 4096) = q3;
        *(unsigned short*)(smem + a_st[4] + ks * 4096) = q4;
        *(unsigned short*)(smem + a_st[5] + ks * 4096) = q5;
        *(unsigned short*)(smem + a_st[6] + ks * 4096) = q6;
        *(unsigned short*)(smem + a_st[7] + ks * 4096) = q7;
      }
      #pragma unroll
      for (int f = 0; f < 4; ++f) {
        bf16x8 a = *(const bf16x8*)(cbf + (h * 64 + f * 16 + ln) * Dd + d0);
        s1[f] = __builtin_amdgcn_mfma_f32_16x16x32_bf16(a, xv, s1[f], 0, 0, 0);
      }
    }

    // -------- softmax over K: 16 lane-local vals + 2 shuffles + cross-half LDS sum
    x2p += __shfl_xor(x2p, 16); x2p += __shfl_xor(x2p, 32);
    const float hx2 = 0.5f * x2p;
    float ssum = 0.f;
    #pragma unroll
    for (int f = 0; f < 4; ++f) {
      #pragma unroll
      for (int r = 0; r < 4; ++r) {
        const float2 ab = tabL[h * 64 + f * 16 + g * 4 + r];   // (alpha, beta)
        const float ev = __expf(ab.x + ab.y * (hx2 - s1[f][r]));
        s1[f][r] = ev;
        ssum += ev;
      }
    }
    ssum += __shfl_xor(ssum, 16); ssum += __shfl_xor(ssum, 32);
    if (g == 0) hs[h][rowLoc] = ssum;
    __syncthreads();   // (1) hs complete (xT also done)

    const float rinv = 1.0f / (hs[0][rowLoc] + hs[1][rowLoc]);
    #pragma unroll
    for (int f = 0; f < 4; ++f) {
      #pragma unroll
      for (int r = 0; r < 4; ++r) {
        const int cwi = h * 64 + f * 16 + g * 4 + r;
        const float wv = s1[f][r] * rinv;
        *(unsigned short*)(Wb + lds_addr((unsigned)cwi, colb)) = f2bf(wv);
        float tsum = wv;                                // sum over this wave's 16 rows
        tsum += __shfl_xor(tsum, 1);
        tsum += __shfl_xor(tsum, 2);
        tsum += __shfl_xor(tsum, 4);
        tsum += __shfl_xor(tsum, 8);
        if (ln == 0) atomicAdd(&WsumL[cwi], tsum);
      }
    }
    __syncthreads();   // (2) W complete

    // -------- Phase 2: E(128x256) += W^T-frags x xT-frags over this 64-row slab
    #pragma unroll
    for (int ks2 = 0; ks2 < 2; ++ks2) {
      const unsigned nb = (unsigned)(ks2 * 32 + g * 8) * 2u;
      bf16x8 af[4], bg[4];
      #pragma unroll
      for (int mi = 0; mi < 4; ++mi)
        af[mi] = *(const bf16x8*)(Wb + lds_addr((unsigned)(wr * 64 + mi * 16 + ln), nb));
      #pragma unroll
      for (int ni = 0; ni < 4; ++ni)
        bg[ni] = *(const bf16x8*)(smem + lds_addr((unsigned)(wc * 64 + ni * 16 + ln), nb));
      #pragma unroll
      for (int mi = 0; mi < 4; ++mi)
        #pragma unroll
        for (int ni = 0; ni < 4; ++ni)
          acc[mi][ni] = __builtin_amdgcn_mfma_f32_16x16x32_bf16(af[mi], bg[ni], acc[mi][ni], 0, 0, 0);
    }
    __syncthreads();   // (3) safe to overwrite xT/W/hs next sub-tile
  }

  // -------- epilogue: Epart[k,d] = acc - Wsum_chunk * c
  #pragma unroll
  for (int mi = 0; mi < 4; ++mi) {
    #pragma unroll
    for (int r = 0; r < 4; ++r) {
      const int cwi = wr * 64 + mi * 16 + g * 4 + r;
      const float wsv = WsumL[cwi];
      #pragma unroll
      for (int ni = 0; ni < 4; ++ni) {
        const int d = wc * 64 + ni * 16 + ln;
        const float v = acc[mi][ni][r] - wsv * cwf[cwi * Dd + d];
        if (PMODE == 0) {
          ((float*)Ep)[(size_t)blockIdx.x * (Kk * Dd) + cwi * Dd + d] = v;
        } else if (PMODE == 1) {
          ((unsigned short*)Ep)[(size_t)blockIdx.x * (Kk * Dd) + cwi * Dd + d] = f2bf(v);
        } else {
          atomicAdd(out + (size_t)b * (Kk * Dd) + cwi * Dd + d, v);
        }
      }
    }
  }
}

__global__ __launch_bounds__(512) void enc_main_f32(
    const float* __restrict__ x, const unsigned short* __restrict__ cbf,
    const float2* __restrict__ tab, const float* __restrict__ cwf,
    char* __restrict__ Ep, float* __restrict__ out) {
  enc_impl<0>(x, cbf, tab, cwf, Ep, out);
}
__global__ __launch_bounds__(512) void enc_main_b16(
    const float* __restrict__ x, const unsigned short* __restrict__ cbf,
    const float2* __restrict__ tab, const float* __restrict__ cwf,
    char* __restrict__ Ep, float* __restrict__ out) {
  enc_impl<1>(x, cbf, tab, cwf, Ep, out);
}
__global__ __launch_bounds__(512) void enc_main_atm(
    const float* __restrict__ x, const unsigned short* __restrict__ cbf,
    const float2* __restrict__ tab, const float* __restrict__ cwf,
    char* __restrict__ Ep, float* __restrict__ out) {
  enc_impl<2>(x, cbf, tab, cwf, nullptr, out);
}

// 16 consecutive floats per thread over 16 chunks: many independent loads in flight.
__global__ __launch_bounds__(256, 1) void enc_reduce_f32(
    const float* __restrict__ Ep, float* __restrict__ out) {
  const size_t i = ((size_t)blockIdx.x * 256 + threadIdx.x) * 16;
  const int b   = (int)(i / (Kk * Dd));
  const int rem = (int)(i % (Kk * Dd));
  const float* p = Ep + (size_t)b * CHUNKS * (Kk * Dd) + rem;
  float sx[16];
  #pragma unroll
  for (int j = 0; j < 16; ++j) sx[j] = 0.f;
  #pragma unroll
  for (int c = 0; c < CHUNKS; ++c) {
    const float4* q = (const float4*)(p + (size_t)c * (Kk * Dd));
    float4 v0 = q[0], v1 = q[1], v2 = q[2], v3 = q[3];
    sx[0] += v0.x; sx[1] += v0.y; sx[2]  += v0.z; sx[3]  += v0.w;
    sx[4] += v1.x; sx[5] += v1.y; sx[6]  += v1.z; sx[7]  += v1.w;
    sx[8] += v2.x; sx[9] += v2.y; sx[10] += v2.z; sx[11] += v2.w;
    sx[12] += v3.x; sx[13] += v3.y; sx[14] += v3.z; sx[15] += v3.w;
  }
  float4* o = (float4*)(out + i);
  o[0] = make_float4(sx[0], sx[1], sx[2], sx[3]);
  o[1] = make_float4(sx[4], sx[5], sx[6], sx[7]);
  o[2] = make_float4(sx[8], sx[9], sx[10], sx[11]);
  o[3] = make_float4(sx[12], sx[13], sx[14], sx[15]);
}

__global__ void enc_reduce_bf16(const unsigned short* __restrict__ Ep, float* __restrict__ out) {
  const size_t i = ((size_t)blockIdx.x * 256 + threadIdx.x) * 8;
  const int b   = (int)(i / (Kk * Dd));
  const int rem = (int)(i % (Kk * Dd));
  const unsigned short* p = Ep + (size_t)b * CHUNKS * (Kk * Dd) + rem;
  float sx[8];
  #pragma unroll
  for (int j = 0; j < 8; ++j) sx[j] = 0.f;
  #pragma unroll
  for (int c = 0; c < CHUNKS; ++c) {
    const ushort4* q = (const ushort4*)(p + (size_t)c * (Kk * Dd));
    ushort4 v0 = q[0], v1 = q[1];
    sx[0] += bf2f(v0.x); sx[1] += bf2f(v0.y); sx[2] += bf2f(v0.z); sx[3] += bf2f(v0.w);
    sx[4] += bf2f(v1.x); sx[5] += bf2f(v1.y); sx[6] += bf2f(v1.z); sx[7] += bf2f(v1.w);
  }
  float4* o = (float4*)(out + i);
  o[0] = make_float4(sx[0], sx[1], sx[2], sx[3]);
  o[1] = make_float4(sx[4], sx[5], sx[6], sx[7]);
}

extern "C" void kernel_launch(void* const* d_in, const int* in_sizes, int n_in,
                              void* d_out, int out_size, void* d_ws, size_t ws_size,
                              hipStream_t stream) {
  const float* x  = (const float*)d_in[0];   // (32, 4096, 256)
  const float* cw = (const float*)d_in[1];   // (128, 256)
  const float* sc = (const float*)d_in[2];   // (128,)
  float* out = (float*)d_out;                // (32, 128, 256)

  unsigned short* cbf = (unsigned short*)d_ws;                    // 64KB bf16 codewords
  float2* tab = (float2*)((char*)d_ws + 65536);                   // 1KB (alpha, beta)
  char*   Ep  = (char*)d_ws + 66560;                              // chunk partials
  const size_t KD = (size_t)Kk * Dd;
  const size_t NBLK = 32 * CHUNKS;                                // 512 blocks
  const size_t needF32 = 66560 + NBLK * KD * 4;                   // ~67.2 MB
  const size_t needB16 = 66560 + NBLK * KD * 2;                   // ~33.6 MB (known to fit)

  enc_prep<<<dim3(Kk), dim3(64), 0, stream>>>(cw, sc, cbf, tab);

  if (ws_size >= needF32) {
    enc_main_f32<<<dim3(NBLK), dim3(512), 0, stream>>>(x, cbf, tab, cw, Ep, out);
    const int rgrid = (int)((32 * KD) / (256 * 16));              // 256 blocks
    enc_reduce_f32<<<dim3(rgrid), dim3(256), 0, stream>>>((const float*)Ep, out);
  } else if (ws_size >= needB16) {
    enc_main_b16<<<dim3(NBLK), dim3(512), 0, stream>>>(x, cbf, tab, cw, Ep, out);
    const int rgrid = (int)((32 * KD) / (256 * 8));               // 512 blocks
    enc_reduce_bf16<<<dim3(rgrid), dim3(256), 0, stream>>>((const unsigned short*)Ep, out);
  } else {
    hipMemsetAsync(d_out, 0, (size_t)out_size * sizeof(float), stream);
    enc_main_atm<<<dim3(NBLK), dim3(512), 0, stream>>>(x, cbf, tab, cw, nullptr, out);
  }
}

// Round 9
// 145.132 us; speedup vs baseline: 1.4881x; 1.4881x over previous
//
#include <hip/hip_runtime.h>

#define DEV __device__ __forceinline__

typedef __attribute__((ext_vector_type(8))) short bf16x8;
typedef __attribute__((ext_vector_type(4))) float f32x4;

constexpr int Nn = 4096, Dd = 256, Kk = 128;
constexpr int SEGS = 16;          // k1 segments per batch (256 rows each)
constexpr int CH2  = 8;           // k2 n-chunks per batch (512 rows each)
constexpr int NCH  = Nn / CH2;    // 512 rows per k2 block
constexpr int NSTEP = 64;         // k2 n-step

DEV unsigned short f2bf(float f) {
  unsigned int u = __builtin_bit_cast(unsigned int, f);
  u += 0x7FFFu + ((u >> 16) & 1u);          // RNE; inputs are finite
  return (unsigned short)(u >> 16);
}
DEV float bf2f(unsigned short h) {
  unsigned int u = (unsigned int)h << 16;
  return __builtin_bit_cast(float, u);
}

// k2 xT tile: row d = 128B (64 bf16 n-values). Swizzle 16B slot by
// hh(d) = (d&7)^((d>>4)&7)^(((d>>7)&1)<<1):
//  - staging writes (lane ln scatters d=ln*16+j): <=4-way (1.58x, writes only)
//  - b128 frag reads (lanes d=base+ln):           <=2-way (free)
DEV unsigned lds2(unsigned d, unsigned nbyte) {
  unsigned hh = (d & 7u) ^ ((d >> 4) & 7u) ^ (((d >> 7) & 1u) << 1);
  return d * 128u + (nbyte ^ (hh << 4));
}

__global__ void enc_prep(const float* __restrict__ cw, const float* __restrict__ sc,
                         unsigned short* __restrict__ cbf, float2* __restrict__ tab) {
  int k = blockIdx.x, l = threadIdx.x;          // 128 blocks x 64 threads
  float4 u = *(const float4*)(cw + k * Dd + l * 4);
  float s2 = u.x * u.x + u.y * u.y + u.z * u.z + u.w * u.w;
  #pragma unroll
  for (int o = 1; o < 64; o <<= 1) s2 += __shfl_xor(s2, o);
  unsigned short* dst = cbf + k * Dd + l * 4;
  dst[0] = f2bf(u.x); dst[1] = f2bf(u.y); dst[2] = f2bf(u.z); dst[3] = f2bf(u.w);
  if (l == 0) { float s = sc[k]; tab[k] = make_float2(s * s2, 2.0f * s); }
}

// ---------------- k1: W^T producer. Fully independent waves, no block sync
// after the 1KB tab stage. Each wave: 16 rows, S^T = mfma(c,x), softmax in
// registers, 32 bf16 stores of W^T[b][k][n].
__global__ __launch_bounds__(1024) void enc_w(
    const float* __restrict__ x, const unsigned short* __restrict__ cbf,
    const float2* __restrict__ tab, unsigned short* __restrict__ Wt) {
  __shared__ float2 tabL[Kk];
  const int tid = threadIdx.x;
  const int w  = tid >> 6;             // wave 0..15
  const int l  = tid & 63;
  const int g  = l >> 4;               // 16-lane group 0..3
  const int ln = l & 15;
  if (tid < Kk) tabL[tid] = tab[tid];
  __syncthreads();

  const int b   = blockIdx.x >> 4;     // 32 batches x 16 segments
  const int seg = blockIdx.x & 15;
  const int nrow = seg * 256 + w * 16 + ln;            // row within batch
  const float* xrow = x + ((size_t)b * Nn + nrow) * Dd;

  f32x4 s1[8];
  const f32x4 zero4 = {0.f, 0.f, 0.f, 0.f};
  #pragma unroll
  for (int f = 0; f < 8; ++f) s1[f] = zero4;
  float x2p = 0.f;

  #pragma unroll
  for (int ks = 0; ks < 8; ++ks) {
    const int d0 = ks * 32 + g * 8;
    float4 u0 = *(const float4*)(xrow + d0);
    float4 u1 = *(const float4*)(xrow + d0 + 4);
    x2p += u0.x*u0.x + u0.y*u0.y + u0.z*u0.z + u0.w*u0.w
         + u1.x*u1.x + u1.y*u1.y + u1.z*u1.z + u1.w*u1.w;
    bf16x8 xv;
    xv[0] = (short)f2bf(u0.x); xv[1] = (short)f2bf(u0.y);
    xv[2] = (short)f2bf(u0.z); xv[3] = (short)f2bf(u0.w);
    xv[4] = (short)f2bf(u1.x); xv[5] = (short)f2bf(u1.y);
    xv[6] = (short)f2bf(u1.z); xv[7] = (short)f2bf(u1.w);
    #pragma unroll
    for (int f = 0; f < 8; ++f) {
      bf16x8 a = *(const bf16x8*)(cbf + (f * 16 + ln) * Dd + d0);
      s1[f] = __builtin_amdgcn_mfma_f32_16x16x32_bf16(a, xv, s1[f], 0, 0, 0);
    }
  }

  x2p += __shfl_xor(x2p, 16); x2p += __shfl_xor(x2p, 32);
  const float hx2 = 0.5f * x2p;
  float ssum = 0.f;
  #pragma unroll
  for (int f = 0; f < 8; ++f) {
    #pragma unroll
    for (int r = 0; r < 4; ++r) {
      const float2 ab = tabL[f * 16 + g * 4 + r];
      const float ev = __expf(ab.x + ab.y * (hx2 - s1[f][r]));
      s1[f][r] = ev;
      ssum += ev;
    }
  }
  ssum += __shfl_xor(ssum, 16); ssum += __shfl_xor(ssum, 32);
  const float rinv = 1.0f / ssum;

  unsigned short* wb = Wt + (size_t)b * Kk * Nn + nrow;
  #pragma unroll
  for (int f = 0; f < 8; ++f) {
    #pragma unroll
    for (int r = 0; r < 4; ++r) {
      const int cwi = f * 16 + g * 4 + r;
      wb[(size_t)cwi * Nn] = f2bf(s1[f][r] * rinv);
    }
  }
}

// ---------------- k2: Ep_chunk[k][d] = sum_n W^T[k][n] x[n][d] - Wsum_chunk[k] c[k][d]
// Double-buffered LDS xT, T14 issue-early/write-late staging, W frags from L2,
// Wsum accumulated from A-fragments in-register. PM: 0 = fp32 partials, 2 = atomic.
template<int PM>
__global__ __launch_bounds__(1024) void enc_e(
    const float* __restrict__ x, const unsigned short* __restrict__ Wt,
    const float* __restrict__ cwf, float* __restrict__ Ep, float* __restrict__ out) {
  __shared__ __align__(16) char xs[2 * 32768];   // xT [256 d][64 n] bf16, dbuf
  __shared__ float wsL[Kk];

  const int tid = threadIdx.x;
  const int w  = tid >> 6;             // wave 0..15
  const int l  = tid & 63;
  const int g  = l >> 4;
  const int ln = l & 15;
  const int wr = w >> 2, wc = w & 3;   // 4x4 wave grid over E(128k x 256d)
  const int b  = blockIdx.x >> 3, ch = blockIdx.x & 7;

  const float* xb = x + ((size_t)b * Nn + ch * NCH) * Dd;
  const unsigned short* Wb = Wt + (size_t)b * Kk * Nn + ch * NCH;

  // staging role: row n_loc = w*4+g (0..63), d-slice = ln*16..+15 (16 floats)
  const int srow = w * 4 + g;
  const int sd0  = ln * 16;
  const unsigned swz0 = lds2((unsigned)(sd0 + 0), (unsigned)(srow * 2)) & 0x7fu; // per-d base varies; compute inline below

  f32x4 acc[2][4];
  const f32x4 zero4 = {0.f, 0.f, 0.f, 0.f};
  #pragma unroll
  for (int mi = 0; mi < 2; ++mi)
    #pragma unroll
    for (int ni = 0; ni < 4; ++ni) acc[mi][ni] = zero4;
  float ws0 = 0.f, ws1 = 0.f;

  // prologue: stage step 0 into buf 0
  {
    const float* p = xb + (size_t)srow * Dd + sd0;
    float4 u0 = *(const float4*)(p + 0), u1 = *(const float4*)(p + 4);
    float4 u2 = *(const float4*)(p + 8), u3 = *(const float4*)(p + 12);
    const float uu[16] = {u0.x,u0.y,u0.z,u0.w, u1.x,u1.y,u1.z,u1.w,
                          u2.x,u2.y,u2.z,u2.w, u3.x,u3.y,u3.z,u3.w};
    #pragma unroll
    for (int j = 0; j < 16; ++j)
      *(unsigned short*)(xs + lds2((unsigned)(sd0 + j), (unsigned)(srow * 2))) = f2bf(uu[j]);
  }
  __syncthreads();

  int cur = 0;
  for (int s = 0; s < CH2; ++s) {          // 8 n-steps of 64
    // T14: issue next step's global loads before compute
    float4 n0, n1, n2, n3;
    if (s + 1 < CH2) {
      const float* p = xb + (size_t)((s + 1) * NSTEP + srow) * Dd + sd0;
      n0 = *(const float4*)(p + 0); n1 = *(const float4*)(p + 4);
      n2 = *(const float4*)(p + 8); n3 = *(const float4*)(p + 12);
    }

    const char* xcur = xs + (cur << 15);
    #pragma unroll
    for (int ks2 = 0; ks2 < 2; ++ks2) {
      const int ncol = s * NSTEP + ks2 * 32 + g * 8;     // within-chunk n of this frag
      bf16x8 af[2], bg[4];
      #pragma unroll
      for (int mi = 0; mi < 2; ++mi)
        af[mi] = *(const bf16x8*)(Wb + (size_t)(wr * 32 + mi * 16 + ln) * Nn + ncol);
      #pragma unroll
      for (int ni = 0; ni < 4; ++ni)
        bg[ni] = *(const bf16x8*)(xcur + lds2((unsigned)(wc * 64 + ni * 16 + ln),
                                              (unsigned)((ks2 * 32 + g * 8) * 2)));
      #pragma unroll
      for (int mi = 0; mi < 2; ++mi) {
        float wsp = 0.f;
        #pragma unroll
        for (int j = 0; j < 8; ++j) wsp += bf2f((unsigned short)af[mi][j]);
        if (mi == 0) ws0 += wsp; else ws1 += wsp;
        #pragma unroll
        for (int ni = 0; ni < 4; ++ni)
          acc[mi][ni] = __builtin_amdgcn_mfma_f32_16x16x32_bf16(af[mi], bg[ni], acc[mi][ni], 0, 0, 0);
      }
    }
    __syncthreads();                        // everyone done reading xs[cur^1]'s successor safely
    if (s + 1 < CH2) {
      char* xn = xs + ((cur ^ 1) << 15);
      const float uu[16] = {n0.x,n0.y,n0.z,n0.w, n1.x,n1.y,n1.z,n1.w,
                            n2.x,n2.y,n2.z,n2.w, n3.x,n3.y,n3.z,n3.w};
      #pragma unroll
      for (int j = 0; j < 16; ++j)
        *(unsigned short*)(xn + lds2((unsigned)(sd0 + j), (unsigned)(srow * 2))) = f2bf(uu[j]);
    }
    __syncthreads();
    cur ^= 1;
  }

  // Wsum_chunk[k]: reduce across g (frags covered disjoint n-slices), publish once
  ws0 += __shfl_xor(ws0, 16); ws0 += __shfl_xor(ws0, 32);
  ws1 += __shfl_xor(ws1, 16); ws1 += __shfl_xor(ws1, 32);
  if (wc == 0 && l < 16) {
    wsL[wr * 32 + l]      = ws0;
    wsL[wr * 32 + 16 + l] = ws1;
  }
  __syncthreads();

  #pragma unroll
  for (int mi = 0; mi < 2; ++mi) {
    #pragma unroll
    for (int r = 0; r < 4; ++r) {
      const int k = wr * 32 + mi * 16 + g * 4 + r;
      const float wsv = wsL[k];
      #pragma unroll
      for (int ni = 0; ni < 4; ++ni) {
        const int d = wc * 64 + ni * 16 + ln;
        const float v = acc[mi][ni][r] - wsv * cwf[k * Dd + d];
        if (PM == 0) {
          Ep[(size_t)blockIdx.x * (Kk * Dd) + k * Dd + d] = v;
        } else {
          atomicAdd(out + (size_t)b * (Kk * Dd) + k * Dd + d, v);
        }
      }
    }
  }
}

// ---------------- k3: out = sum over 8 chunk-partials (16 floats/thread)
__global__ __launch_bounds__(256, 1) void enc_reduce_f32(
    const float* __restrict__ Ep, float* __restrict__ out) {
  const size_t i = ((size_t)blockIdx.x * 256 + threadIdx.x) * 16;
  const int b   = (int)(i / (Kk * Dd));
  const int rem = (int)(i % (Kk * Dd));
  const float* p = Ep + (size_t)b * CH2 * (Kk * Dd) + rem;
  float sx[16];
  #pragma unroll
  for (int j = 0; j < 16; ++j) sx[j] = 0.f;
  #pragma unroll
  for (int c = 0; c < CH2; ++c) {
    const float4* q = (const float4*)(p + (size_t)c * (Kk * Dd));
    float4 v0 = q[0], v1 = q[1], v2 = q[2], v3 = q[3];
    sx[0] += v0.x; sx[1] += v0.y; sx[2]  += v0.z; sx[3]  += v0.w;
    sx[4] += v1.x; sx[5] += v1.y; sx[6]  += v1.z; sx[7]  += v1.w;
    sx[8] += v2.x; sx[9] += v2.y; sx[10] += v2.z; sx[11] += v2.w;
    sx[12] += v3.x; sx[13] += v3.y; sx[14] += v3.z; sx[15] += v3.w;
  }
  float4* o = (float4*)(out + i);
  o[0] = make_float4(sx[0], sx[1], sx[2], sx[3]);
  o[1] = make_float4(sx[4], sx[5], sx[6], sx[7]);
  o[2] = make_float4(sx[8], sx[9], sx[10], sx[11]);
  o[3] = make_float4(sx[12], sx[13], sx[14], sx[15]);
}

extern "C" void kernel_launch(void* const* d_in, const int* in_sizes, int n_in,
                              void* d_out, int out_size, void* d_ws, size_t ws_size,
                              hipStream_t stream) {
  const float* x  = (const float*)d_in[0];   // (32, 4096, 256)
  const float* cw = (const float*)d_in[1];   // (128, 256)
  const float* sc = (const float*)d_in[2];   // (128,)
  float* out = (float*)d_out;                // (32, 128, 256)

  unsigned short* cbf = (unsigned short*)d_ws;                      // 64KB
  float2* tab = (float2*)((char*)d_ws + 65536);                     // 1KB
  unsigned short* Wt = (unsigned short*)((char*)d_ws + 66560);      // 33.55MB W^T bf16
  float* Ep = (float*)((char*)d_ws + 66560 + (size_t)32 * Kk * Nn * 2);  // 33.55MB fp32
  const size_t KD = (size_t)Kk * Dd;
  const size_t needFull = 66560 + (size_t)32 * Kk * Nn * 2 + (size_t)32 * CH2 * KD * 4; // 67,175,424 (== r8 proven)
  const size_t needAtm  = 66560 + (size_t)32 * Kk * Nn * 2;

  enc_prep<<<dim3(Kk), dim3(64), 0, stream>>>(cw, sc, cbf, tab);
  enc_w<<<dim3(32 * SEGS), dim3(1024), 0, stream>>>(x, cbf, tab, Wt);

  if (ws_size >= needFull) {
    enc_e<0><<<dim3(32 * CH2), dim3(1024), 0, stream>>>(x, Wt, cw, Ep, nullptr);
    enc_reduce_f32<<<dim3(256), dim3(256), 0, stream>>>(Ep, out);
  } else if (ws_size >= needAtm) {
    hipMemsetAsync(d_out, 0, (size_t)out_size * sizeof(float), stream);
    enc_e<2><<<dim3(32 * CH2), dim3(1024), 0, stream>>>(x, Wt, cw, nullptr, out);
  }
}